// Round 1
// baseline (473.841 us; speedup 1.0000x reference)
//
#include <hip/hip_runtime.h>

#define GN 8192
#define GF 256
#define SLOPE 0.2f

// ---------------------------------------------------------------------------
// Probe: classify adjacency storage. mode 0 = int32, 1 = uint8, 2 = float32.
// Scans first 16384 words (64 KB) — safe for all encodings (min buffer 64 MB).
// int32 bool  -> words in {0,1} only
// uint8 bool  -> packed bytes in {0,1}: some word >1 with (w & 0xFEFEFEFE)==0
// float32     -> 1.0f words == 0x3F800000
// Diagonal is guaranteed true and density is 5%, so the signal is certain.
// ---------------------------------------------------------------------------
__global__ void detect_mode_kernel(const unsigned int* __restrict__ adj,
                                   int* __restrict__ mode) {
    __shared__ int s_byte, s_float;
    if (threadIdx.x == 0) { s_byte = 0; s_float = 0; }
    __syncthreads();
    int any_byte = 0, any_float = 0;
    for (int i = threadIdx.x; i < 16384; i += 256) {
        unsigned int w = adj[i];
        if (w == 0x3F800000u) any_float = 1;
        else if (w > 1u && (w & 0xFEFEFEFEu) == 0u) any_byte = 1;
    }
    if (any_byte)  atomicOr(&s_byte, 1);
    if (any_float) atomicOr(&s_float, 1);
    __syncthreads();
    if (threadIdx.x == 0) *mode = s_byte ? 1 : (s_float ? 2 : 0);
}

// ---------------------------------------------------------------------------
// e = h @ a  (8192x256 @ 256x2). One 64-lane wave per row, float4 loads,
// butterfly shuffle reduction. Trivial cost (~8 MB read).
// a is (256,2) row-major: a[f][0]=a[2f], a[f][1]=a[2f+1].
// ---------------------------------------------------------------------------
__global__ __launch_bounds__(256) void compute_e_kernel(
        const float* __restrict__ h, const float* __restrict__ a,
        float* __restrict__ e1, float* __restrict__ e2) {
    int wave = threadIdx.x >> 6;
    int lane = threadIdx.x & 63;
    int row  = blockIdx.x * 4 + wave;

    const float4* h4 = (const float4*)(h + (size_t)row * GF);
    float4 hv = h4[lane];                       // features lane*4 .. lane*4+3
    const float4* a4 = (const float4*)a;
    float4 av0 = a4[2 * lane];                  // {a[f0,0],a[f0,1],a[f1,0],a[f1,1]}
    float4 av1 = a4[2 * lane + 1];              // {a[f2,0],a[f2,1],a[f3,0],a[f3,1]}

    float d1 = hv.x * av0.x + hv.y * av0.z + hv.z * av1.x + hv.w * av1.z;
    float d2 = hv.x * av0.y + hv.y * av0.w + hv.z * av1.y + hv.w * av1.w;
    #pragma unroll
    for (int off = 32; off; off >>= 1) {
        d1 += __shfl_xor(d1, off);
        d2 += __shfl_xor(d2, off);
    }
    if (lane == 0) {
        e1[row] = d1;
        e2[row] = d2;
    }
}

// ---------------------------------------------------------------------------
// Main: one block per row. Each thread owns 32 columns (8 float4 chunks).
// Phase 1: masked exp into registers + block sum. Phase 2: scale + store.
// Adjacency read exactly once from HBM; output written exactly once.
// No max-subtraction: |e1+e2| <~ 14, exp safe in fp32, error ~1e-6 rel.
// ---------------------------------------------------------------------------
template <int MODE>
__device__ __forceinline__ void attn_row_body(
        const void* __restrict__ adjv,
        const float* __restrict__ e1, const float* __restrict__ e2,
        float* __restrict__ out) {
    const int row = blockIdx.x;
    const int tid = threadIdx.x;
    const float se1 = e1[row];
    const size_t rowbase = (size_t)row * GN;     // element index
    const size_t vecbase = rowbase >> 2;         // float4/int4/uint index

    const float4* e2v = (const float4*)e2;

    float v[32];
    float acc = 0.f;

    #pragma unroll
    for (int c = 0; c < 8; ++c) {
        const int j4 = c * 256 + tid;            // vec4 index within row
        float4 ev = e2v[j4];
        bool m0, m1, m2, m3;
        if (MODE == 0) {
            int4 aw = ((const int4*)adjv)[vecbase + j4];
            m0 = aw.x != 0; m1 = aw.y != 0; m2 = aw.z != 0; m3 = aw.w != 0;
        } else if (MODE == 1) {
            unsigned int aw = ((const unsigned int*)adjv)[vecbase + j4];
            m0 = (aw & 0x000000FFu) != 0; m1 = (aw & 0x0000FF00u) != 0;
            m2 = (aw & 0x00FF0000u) != 0; m3 = (aw & 0xFF000000u) != 0;
        } else {
            float4 aw = ((const float4*)adjv)[vecbase + j4];
            m0 = aw.x != 0.f; m1 = aw.y != 0.f; m2 = aw.z != 0.f; m3 = aw.w != 0.f;
        }
        float s0 = se1 + ev.x; s0 = s0 >= 0.f ? s0 : SLOPE * s0;
        float s1 = se1 + ev.y; s1 = s1 >= 0.f ? s1 : SLOPE * s1;
        float s2 = se1 + ev.z; s2 = s2 >= 0.f ? s2 : SLOPE * s2;
        float s3 = se1 + ev.w; s3 = s3 >= 0.f ? s3 : SLOPE * s3;
        float x0 = m0 ? __expf(s0) : 0.f;
        float x1 = m1 ? __expf(s1) : 0.f;
        float x2 = m2 ? __expf(s2) : 0.f;
        float x3 = m3 ? __expf(s3) : 0.f;
        v[c * 4 + 0] = x0; v[c * 4 + 1] = x1;
        v[c * 4 + 2] = x2; v[c * 4 + 3] = x3;
        acc += x0 + x1 + x2 + x3;
    }

    // block reduction: 64-lane butterfly, then 4 wave partials through LDS
    #pragma unroll
    for (int off = 32; off; off >>= 1) acc += __shfl_xor(acc, off);
    __shared__ float wsum[4];
    if ((tid & 63) == 0) wsum[tid >> 6] = acc;
    __syncthreads();
    const float total = wsum[0] + wsum[1] + wsum[2] + wsum[3];
    const float inv = 1.0f / total;

    float4* out4 = (float4*)(out + rowbase);
    #pragma unroll
    for (int c = 0; c < 8; ++c) {
        float4 o;
        o.x = v[c * 4 + 0] * inv; o.y = v[c * 4 + 1] * inv;
        o.z = v[c * 4 + 2] * inv; o.w = v[c * 4 + 3] * inv;
        out4[c * 256 + tid] = o;
    }
}

__global__ __launch_bounds__(256) void attn_row_kernel(
        const int* __restrict__ mode, const void* __restrict__ adjv,
        const float* __restrict__ e1, const float* __restrict__ e2,
        float* __restrict__ out) {
    const int m = *mode;   // uniform across grid
    if (m == 0)      attn_row_body<0>(adjv, e1, e2, out);
    else if (m == 1) attn_row_body<1>(adjv, e1, e2, out);
    else             attn_row_body<2>(adjv, e1, e2, out);
}

extern "C" void kernel_launch(void* const* d_in, const int* in_sizes, int n_in,
                              void* d_out, int out_size, void* d_ws, size_t ws_size,
                              hipStream_t stream) {
    const float* h   = (const float*)d_in[0];
    const void*  adj = (const void*)d_in[1];
    const float* a   = (const float*)d_in[2];
    float* out = (float*)d_out;

    int*   mode = (int*)d_ws;
    float* e1   = (float*)((char*)d_ws + 256);
    float* e2   = e1 + GN;

    detect_mode_kernel<<<1, 256, 0, stream>>>((const unsigned int*)adj, mode);
    compute_e_kernel<<<GN / 4, 256, 0, stream>>>(h, a, e1, e2);
    attn_row_kernel<<<GN, 256, 0, stream>>>(mode, adj, e1, e2, out);
}

// Round 3
// 437.654 us; speedup vs baseline: 1.0827x; 1.0827x over previous
//
#include <hip/hip_runtime.h>

#define GN 8192
#define GF 256
#define SLOPE 0.2f

// Native clang vector types — required by __builtin_nontemporal_load/store
// (HIP_vector_type structs are rejected by the builtin).
typedef int   vint4   __attribute__((ext_vector_type(4)));
typedef float vfloat4 __attribute__((ext_vector_type(4)));

// ---------------------------------------------------------------------------
// e = h @ a  (8192x256 @ 256x2). One 64-lane wave per row, float4 loads,
// butterfly shuffle reduction. ~8 MB read, ~10 us.
// a is (256,2) row-major: a[f][0]=a[2f], a[f][1]=a[2f+1].
// ---------------------------------------------------------------------------
__global__ __launch_bounds__(256) void compute_e_kernel(
        const float* __restrict__ h, const float* __restrict__ a,
        float* __restrict__ e1, float* __restrict__ e2) {
    int wave = threadIdx.x >> 6;
    int lane = threadIdx.x & 63;
    int row  = blockIdx.x * 4 + wave;

    const float4* h4 = (const float4*)(h + (size_t)row * GF);
    float4 hv = h4[lane];                       // features lane*4 .. lane*4+3
    const float4* a4 = (const float4*)a;
    float4 av0 = a4[2 * lane];                  // {a[f0,0],a[f0,1],a[f1,0],a[f1,1]}
    float4 av1 = a4[2 * lane + 1];              // {a[f2,0],a[f2,1],a[f3,0],a[f3,1]}

    float d1 = hv.x * av0.x + hv.y * av0.z + hv.z * av1.x + hv.w * av1.z;
    float d2 = hv.x * av0.y + hv.y * av0.w + hv.z * av1.y + hv.w * av1.w;
    #pragma unroll
    for (int off = 32; off; off >>= 1) {
        d1 += __shfl_xor(d1, off);
        d2 += __shfl_xor(d2, off);
    }
    if (lane == 0) {
        e1[row] = d1;
        e2[row] = d2;
    }
}

// ---------------------------------------------------------------------------
// Main: one block (512 threads) per row. Each thread owns 16 columns
// (4 vec4 chunks). Self-classifies adjacency encoding from the buffer head
// (first 2048 words — part of row 0 in every encoding; diagonal + 5%
// density make the signal deterministic):
//   mode 0: int32 bools  — all words in {0,1}
//   mode 1: uint8 bools  — some word >1 with (w & 0xFEFEFEFE)==0 (~290/2048)
//   mode 2: float32      — some word == 0x3F800000 (>=1 guaranteed: diagonal)
// Phase 1: masked exp into registers + block sum. Phase 2: scale + store.
// Adjacency streamed once (nontemporal); output written once (nontemporal).
// No max-subtraction: |e1+e2| <~ 14, exp safe in fp32.
// ---------------------------------------------------------------------------
template <int MODE>
__device__ __forceinline__ void attn_row_body(
        const void* __restrict__ adjv,
        const float* __restrict__ e1, const float* __restrict__ e2,
        float* __restrict__ out, float* __restrict__ wsum) {
    const int row = blockIdx.x;
    const int tid = threadIdx.x;
    const float se1 = e1[row];
    const size_t rowbase = (size_t)row * GN;     // output element index
    const size_t vecbase = (size_t)row * 2048;   // vec4 (or uint-word) index

    const float4* e2v = (const float4*)e2;

    float v[16];
    float acc = 0.f;

    #pragma unroll
    for (int c = 0; c < 4; ++c) {
        const int j4 = c * 512 + tid;            // vec4-of-columns index
        float4 ev = e2v[j4];
        bool m0, m1, m2, m3;
        if (MODE == 0) {
            vint4 aw = __builtin_nontemporal_load(&((const vint4*)adjv)[vecbase + j4]);
            m0 = aw.x != 0; m1 = aw.y != 0; m2 = aw.z != 0; m3 = aw.w != 0;
        } else if (MODE == 1) {
            unsigned int aw = __builtin_nontemporal_load(&((const unsigned int*)adjv)[vecbase + j4]);
            m0 = (aw & 0x000000FFu) != 0; m1 = (aw & 0x0000FF00u) != 0;
            m2 = (aw & 0x00FF0000u) != 0; m3 = (aw & 0xFF000000u) != 0;
        } else {
            vfloat4 aw = __builtin_nontemporal_load(&((const vfloat4*)adjv)[vecbase + j4]);
            m0 = aw.x != 0.f; m1 = aw.y != 0.f; m2 = aw.z != 0.f; m3 = aw.w != 0.f;
        }
        float s0 = se1 + ev.x; s0 = s0 >= 0.f ? s0 : SLOPE * s0;
        float s1 = se1 + ev.y; s1 = s1 >= 0.f ? s1 : SLOPE * s1;
        float s2 = se1 + ev.z; s2 = s2 >= 0.f ? s2 : SLOPE * s2;
        float s3 = se1 + ev.w; s3 = s3 >= 0.f ? s3 : SLOPE * s3;
        float x0 = m0 ? __expf(s0) : 0.f;
        float x1 = m1 ? __expf(s1) : 0.f;
        float x2 = m2 ? __expf(s2) : 0.f;
        float x3 = m3 ? __expf(s3) : 0.f;
        v[c * 4 + 0] = x0; v[c * 4 + 1] = x1;
        v[c * 4 + 2] = x2; v[c * 4 + 3] = x3;
        acc += x0 + x1 + x2 + x3;
    }

    // block reduction: 64-lane butterfly, then 8 wave partials through LDS
    #pragma unroll
    for (int off = 32; off; off >>= 1) acc += __shfl_xor(acc, off);
    if ((tid & 63) == 0) wsum[tid >> 6] = acc;
    __syncthreads();
    float total = 0.f;
    #pragma unroll
    for (int w = 0; w < 8; ++w) total += wsum[w];
    const float inv = 1.0f / total;

    vfloat4* out4 = (vfloat4*)(out + rowbase);
    #pragma unroll
    for (int c = 0; c < 4; ++c) {
        vfloat4 o;
        o.x = v[c * 4 + 0] * inv; o.y = v[c * 4 + 1] * inv;
        o.z = v[c * 4 + 2] * inv; o.w = v[c * 4 + 3] * inv;
        __builtin_nontemporal_store(o, &out4[c * 512 + tid]);
    }
}

__global__ __launch_bounds__(512) void attn_row_kernel(
        const void* __restrict__ adjv,
        const float* __restrict__ e1, const float* __restrict__ e2,
        float* __restrict__ out) {
    __shared__ int s_flags;
    __shared__ float wsum[8];
    const int tid = threadIdx.x;
    if (tid == 0) s_flags = 0;
    __syncthreads();

    // Self-classify from buffer head (same 8 KB for all blocks -> L2 broadcast)
    uint4 hw = ((const uint4*)adjv)[tid];        // words 0..2047
    int f = 0;
    {
        unsigned int w;
        w = hw.x; if (w == 0x3F800000u) f |= 2; else if (w > 1u && (w & 0xFEFEFEFEu) == 0u) f |= 1;
        w = hw.y; if (w == 0x3F800000u) f |= 2; else if (w > 1u && (w & 0xFEFEFEFEu) == 0u) f |= 1;
        w = hw.z; if (w == 0x3F800000u) f |= 2; else if (w > 1u && (w & 0xFEFEFEFEu) == 0u) f |= 1;
        w = hw.w; if (w == 0x3F800000u) f |= 2; else if (w > 1u && (w & 0xFEFEFEFEu) == 0u) f |= 1;
    }
    if (f) atomicOr(&s_flags, f);
    __syncthreads();
    const int mode = (s_flags & 1) ? 1 : ((s_flags & 2) ? 2 : 0);

    if (mode == 0)      attn_row_body<0>(adjv, e1, e2, out, wsum);
    else if (mode == 1) attn_row_body<1>(adjv, e1, e2, out, wsum);
    else                attn_row_body<2>(adjv, e1, e2, out, wsum);
}

extern "C" void kernel_launch(void* const* d_in, const int* in_sizes, int n_in,
                              void* d_out, int out_size, void* d_ws, size_t ws_size,
                              hipStream_t stream) {
    const float* h   = (const float*)d_in[0];
    const void*  adj = (const void*)d_in[1];
    const float* a   = (const float*)d_in[2];
    float* out = (float*)d_out;

    float* e1 = (float*)d_ws;
    float* e2 = e1 + GN;

    compute_e_kernel<<<GN / 4, 256, 0, stream>>>(h, a, e1, e2);
    attn_row_kernel<<<GN, 512, 0, stream>>>(adj, e1, e2, out);
}

// Round 4
// 427.294 us; speedup vs baseline: 1.1089x; 1.0242x over previous
//
#include <hip/hip_runtime.h>

#define GN 8192
#define GF 256
#define SLOPE 0.2f

// Native clang vector types — __builtin_nontemporal_load/store reject the
// HIP_vector_type structs (int4/float4); ext_vector_type works.
typedef int   vint4   __attribute__((ext_vector_type(4)));
typedef float vfloat4 __attribute__((ext_vector_type(4)));

// ---------------------------------------------------------------------------
// e = h @ a  (8192x256 @ 256x2), one 64-lane wave per row; plus block 0
// classifies the adjacency storage encoding once (first 2048 words = start of
// row 0 in every encoding; diagonal + 5% density make it deterministic):
//   mode 0: int32 bools  — all words in {0,1}
//   mode 1: uint8 bools  — some word >1 with (w & 0xFEFEFEFE)==0
//   mode 2: float32      — some word == 0x3F800000 (word 0 is diag -> 1.0f)
// ---------------------------------------------------------------------------
__global__ __launch_bounds__(256) void compute_e_kernel(
        const float* __restrict__ h, const float* __restrict__ a,
        const unsigned int* __restrict__ adjw,
        float* __restrict__ e1, float* __restrict__ e2,
        int* __restrict__ mode) {
    if (blockIdx.x == 0) {
        __shared__ int s_flags;
        if (threadIdx.x == 0) s_flags = 0;
        __syncthreads();
        int f = 0;
        for (int i = threadIdx.x; i < 2048; i += 256) {
            unsigned int w = adjw[i];
            if (w == 0x3F800000u) f |= 2;
            else if (w > 1u && (w & 0xFEFEFEFEu) == 0u) f |= 1;
        }
        if (f) atomicOr(&s_flags, f);
        __syncthreads();
        if (threadIdx.x == 0)
            *mode = (s_flags & 1) ? 1 : ((s_flags & 2) ? 2 : 0);
    }

    int wave = threadIdx.x >> 6;
    int lane = threadIdx.x & 63;
    int row  = blockIdx.x * 4 + wave;

    const float4* h4 = (const float4*)(h + (size_t)row * GF);
    float4 hv = h4[lane];
    const float4* a4 = (const float4*)a;
    float4 av0 = a4[2 * lane];                  // {a[f0,0],a[f0,1],a[f1,0],a[f1,1]}
    float4 av1 = a4[2 * lane + 1];

    float d1 = hv.x * av0.x + hv.y * av0.z + hv.z * av1.x + hv.w * av1.z;
    float d2 = hv.x * av0.y + hv.y * av0.w + hv.z * av1.y + hv.w * av1.w;
    #pragma unroll
    for (int off = 32; off; off >>= 1) {
        d1 += __shfl_xor(d1, off);
        d2 += __shfl_xor(d2, off);
    }
    if (lane == 0) {
        e1[row] = d1;
        e2[row] = d2;
    }
}

// ---------------------------------------------------------------------------
// Main: one block (512 threads) per row; each thread owns 16 cols (4 vec4).
// Phase 1: masked exp into registers + block sum; phase 2: scale + nt store.
// Adjacency streamed once (nontemporal, no reuse); output written once (nt).
// Mask applied by MULTIPLY (words/bytes are {0,1}): no cmp/cndmask.
// Leaky ReLU = fmax(s, 0.2*s) — valid for slope in (0,1).
// No max-subtraction: |e1+e2| <~ 14, exp safe in fp32.
// ---------------------------------------------------------------------------
template <int MODE>
__device__ __forceinline__ void attn_row_body(
        const void* __restrict__ adjv,
        const float* __restrict__ e1, const float* __restrict__ e2,
        float* __restrict__ out, float* __restrict__ wsum) {
    const int row = blockIdx.x;
    const int tid = threadIdx.x;
    const float se1 = e1[row];
    const size_t rowbase = (size_t)row * GN;     // output element index
    const size_t vecbase = (size_t)row * 2048;   // vec4 (or uint-word) index

    const float4* e2v = (const float4*)e2;

    float v[16];
    float acc = 0.f;

    #pragma unroll
    for (int c = 0; c < 4; ++c) {
        const int j4 = c * 512 + tid;            // vec4-of-columns index
        float4 ev = e2v[j4];
        float m0, m1, m2, m3;                    // 0.0 or 1.0
        if (MODE == 0) {
            vint4 aw = __builtin_nontemporal_load(&((const vint4*)adjv)[vecbase + j4]);
            m0 = (float)aw.x; m1 = (float)aw.y; m2 = (float)aw.z; m3 = (float)aw.w;
        } else if (MODE == 1) {
            unsigned int aw = __builtin_nontemporal_load(&((const unsigned int*)adjv)[vecbase + j4]);
            m0 = (float)(aw & 0xFFu);            // v_cvt_f32_ubyte0
            m1 = (float)((aw >> 8) & 0xFFu);     // v_cvt_f32_ubyte1
            m2 = (float)((aw >> 16) & 0xFFu);    // v_cvt_f32_ubyte2
            m3 = (float)(aw >> 24);              // v_cvt_f32_ubyte3
        } else {
            vfloat4 aw = __builtin_nontemporal_load(&((const vfloat4*)adjv)[vecbase + j4]);
            m0 = aw.x; m1 = aw.y; m2 = aw.z; m3 = aw.w;
        }
        float s0 = se1 + ev.x; s0 = fmaxf(s0, SLOPE * s0);
        float s1 = se1 + ev.y; s1 = fmaxf(s1, SLOPE * s1);
        float s2 = se1 + ev.z; s2 = fmaxf(s2, SLOPE * s2);
        float s3 = se1 + ev.w; s3 = fmaxf(s3, SLOPE * s3);
        float x0 = __expf(s0) * m0;
        float x1 = __expf(s1) * m1;
        float x2 = __expf(s2) * m2;
        float x3 = __expf(s3) * m3;
        v[c * 4 + 0] = x0; v[c * 4 + 1] = x1;
        v[c * 4 + 2] = x2; v[c * 4 + 3] = x3;
        acc += (x0 + x1) + (x2 + x3);
    }

    // block reduction: 64-lane butterfly, then 8 wave partials through LDS
    #pragma unroll
    for (int off = 32; off; off >>= 1) acc += __shfl_xor(acc, off);
    if ((tid & 63) == 0) wsum[tid >> 6] = acc;
    __syncthreads();
    float total = 0.f;
    #pragma unroll
    for (int w = 0; w < 8; ++w) total += wsum[w];   // same-addr LDS broadcast
    const float inv = 1.0f / total;

    vfloat4* out4 = (vfloat4*)(out + rowbase);
    #pragma unroll
    for (int c = 0; c < 4; ++c) {
        vfloat4 o;
        o.x = v[c * 4 + 0] * inv; o.y = v[c * 4 + 1] * inv;
        o.z = v[c * 4 + 2] * inv; o.w = v[c * 4 + 3] * inv;
        __builtin_nontemporal_store(o, &out4[c * 512 + tid]);
    }
}

__global__ __launch_bounds__(512) void attn_row_kernel(
        const int* __restrict__ mode, const void* __restrict__ adjv,
        const float* __restrict__ e1, const float* __restrict__ e2,
        float* __restrict__ out) {
    __shared__ float wsum[8];
    const int m = *mode;   // uniform across grid (L2 broadcast)
    if (m == 0)      attn_row_body<0>(adjv, e1, e2, out, wsum);
    else if (m == 1) attn_row_body<1>(adjv, e1, e2, out, wsum);
    else             attn_row_body<2>(adjv, e1, e2, out, wsum);
}

extern "C" void kernel_launch(void* const* d_in, const int* in_sizes, int n_in,
                              void* d_out, int out_size, void* d_ws, size_t ws_size,
                              hipStream_t stream) {
    const float* h   = (const float*)d_in[0];
    const void*  adj = (const void*)d_in[1];
    const float* a   = (const float*)d_in[2];
    float* out = (float*)d_out;

    float* e1   = (float*)d_ws;
    float* e2   = e1 + GN;
    int*   mode = (int*)(e2 + GN);

    compute_e_kernel<<<GN / 4, 256, 0, stream>>>(h, a, (const unsigned int*)adj,
                                                 e1, e2, mode);
    attn_row_kernel<<<GN, 512, 0, stream>>>(mode, adj, e1, e2, out);
}